// Round 3
// baseline (21378.439 us; speedup 1.0000x reference)
//
#include <hip/hip_runtime.h>
#include <math.h>

#define NB 64
#define NT 1024
#define NI 128
#define NH 512

// ---------------------------------------------------------------------------
// prep: transpose input-proj weights to k-major [k][j*4+m], init h (both
// double-buffer halves) = 1, zero barrier words.
// ---------------------------------------------------------------------------
__global__ __launch_bounds__(256) void prep_kernel(
    const float* __restrict__ Wsw, const float* __restrict__ Wsm,
    const float* __restrict__ Wss, const float* __restrict__ Wtcx,
    float* __restrict__ WT_in, float* __restrict__ hbuf, unsigned* __restrict__ bar)
{
  int idx = blockIdx.x * blockDim.x + threadIdx.x;
  int np  = gridDim.x * blockDim.x;
  for (int i = idx; i < NH * NI; i += np) {
    int j = i >> 7, k = i & 127;            // W is [H][I] row-major
    int o = k * 2048 + j * 4;
    WT_in[o + 0] = Wsw[i];
    WT_in[o + 1] = Wsm[i];
    WT_in[o + 2] = Wss[i];
    WT_in[o + 3] = Wtcx[i];
  }
  for (int i = idx; i < 2 * NB * NH; i += np) hbuf[i] = 1.0f;
  for (int i = idx; i < 256; i += np) bar[i] = 0u;
}

// ---------------------------------------------------------------------------
// phase1: sensory + tcx for all (b,t).  Block = 32 rows x all 512 j.
// ---------------------------------------------------------------------------
__global__ __launch_bounds__(256, 2) void phase1_kernel(
    const float* __restrict__ x, const float* __restrict__ WT_in,
    const float* __restrict__ bsw, const float* __restrict__ bsm,
    const float* __restrict__ bss, const float* __restrict__ btc,
    float* __restrict__ sens, float* __restrict__ tcx)
{
  __shared__ __align__(16) float xs[32 * NI];   // 16 KB
  const int tid = threadIdx.x;
  const int n0  = blockIdx.x * 32;

  const float4* xsrc = (const float4*)(x + (size_t)n0 * NI);
#pragma unroll
  for (int i = 0; i < 4; i++)
    ((float4*)xs)[i * 256 + tid] = xsrc[i * 256 + tid];
  __syncthreads();

  for (int jj = 0; jj < 2; jj++) {
    const int j = tid + jj * 256;
    float4 acc[32];
#pragma unroll
    for (int n = 0; n < 32; n++) acc[n] = make_float4(0.f, 0.f, 0.f, 0.f);

    const float4* wp = (const float4*)WT_in + j;   // row k at wp[k*512]
#pragma unroll 2
    for (int k = 0; k < NI; k++) {
      float4 w = wp[(size_t)k * 512];
#pragma unroll
      for (int n = 0; n < 32; n++) {
        float xv = xs[n * NI + k];
        acc[n].x = fmaf(xv, w.x, acc[n].x);
        acc[n].y = fmaf(xv, w.y, acc[n].y);
        acc[n].z = fmaf(xv, w.z, acc[n].z);
        acc[n].w = fmaf(xv, w.w, acc[n].w);
      }
    }
    const float b0 = bsw[j], b1 = bsm[j], b2v = bss[j], b3 = btc[j];
#pragma unroll 4
    for (int n = 0; n < 32; n++) {
      float sw = acc[n].x + b0;
      float sm = acc[n].y + b1;
      float ss = acc[n].z + b2v;
      float tc = acc[n].w + b3;
      float sig = 1.f / (1.f + expf(-sm));
      float se  = expf(fminf(ss, 50.f));
      size_t o = (size_t)(n0 + n) * NH + j;
      sens[o] = sw * sig * se;
      tcx[o]  = tc;
    }
  }
}

// ---------------------------------------------------------------------------
// phase2: persistent recurrent scan.
// 256 blocks = 8 batch-groups (bg = blockIdx&7, 8 batches each) x 32 j-slices
// (16 j each -> 64 gate-columns).  Weights live in VGPRs for all 1024 steps.
// h is DOUBLE-BUFFERED in global memory: step t reads hbuf[t&1], writes
// hbuf[(t+1)&1].  One per-group agent-scope barrier per step.
// REGULAR launch (round-2 fix): grid=256 blocks at 1 block/CU on a 256-CU
// device -> full co-residency without the cooperative-launch API, whose
// silent failure (unchecked return) left phase2 unexecuted in rounds 1-2
// (bit-identical absmax across differing phase2 kernels proved out==sens).
// ---------------------------------------------------------------------------
__global__ __launch_bounds__(256, 1) void phase2_kernel(
    const float* __restrict__ Wiw, const float* __restrict__ Wim,
    const float* __restrict__ Wis, const float* __restrict__ Wtch,
    const float* __restrict__ biw, const float* __restrict__ bim,
    const float* __restrict__ bis,
    const float* __restrict__ tcx, float* __restrict__ out,
    float* __restrict__ hglob, unsigned* __restrict__ bar)
{
  __shared__ __align__(16) float hl[8 * 576];   // 18432 B, skewed h tile
  __shared__ float red[4 * 528];                // 8448 B reduction scratch

  const int tid = threadIdx.x;
  const int wv  = tid >> 6;
  const int ln  = tid & 63;
  const int bg  = blockIdx.x & 7;
  const int js  = blockIdx.x >> 3;

  const int cg = ln & 15;
  const int r  = wv * 4 + (ln >> 4);   // k-range id 0..15
  const int k0 = r << 5;

  // persistent weights (128 VGPRs): col c = cg + 16*ci, gate g = cg&3
  const int g   = cg & 3;
  const int jl0 = cg >> 2;
  const float* Wp = (g == 0) ? Wiw : (g == 1) ? Wim : (g == 2) ? Wis : Wtch;
  float wreg[4][32];
#pragma unroll
  for (int ci = 0; ci < 4; ci++) {
    const float* wrow = Wp + (size_t)(js * 16 + jl0 + 4 * ci) * NH + k0;
#pragma unroll
    for (int kk = 0; kk < 32; kk++) wreg[ci][kk] = wrow[kk];
  }

  // epilogue-thread constants (tid<128 handles (b = tid>>4, jl = tid&15))
  const int ejl = tid & 15;
  const int eb  = tid >> 4;
  const int ej  = js * 16 + ejl;
  float bw = 0.f, bm = 0.f, bs = 0.f;
  if (tid < 128) { bw = biw[ej]; bm = bim[ej]; bs = bis[ej]; }

  unsigned* cnt = bar + bg * 32;
  unsigned* gen = bar + bg * 32 + 16;   // separate 64B line from cnt

  for (int t = 0; t < NT; t++) {
    const float* hsrc = hglob + (size_t)(t & 1) * (NB * NH);
    float*       hdst = hglob + (size_t)((t + 1) & 1) * (NB * NH);

    // ---- stage h(t) -> LDS (skewed) ----
#pragma unroll
    for (int i = 0; i < 4; i++) {
      int flat = i * 1024 + tid * 4;
      int b2 = flat >> 9, k = flat & 511;
      float4 hv = *(const float4*)(hsrc + bg * 4096 + flat);
      *(float4*)(hl + b2 * 576 + (k >> 5) * 36 + (k & 31)) = hv;
    }
    // ---- prefetch sens/tcx (consumed after K-loop) ----
    float sens_v = 0.f, tcx_v = 0.f;
    size_t eidx = 0;
    if (tid < 128) {
      eidx   = ((size_t)(bg * 8 + eb) * NT + t) * NH + ej;
      sens_v = out[eidx];
      tcx_v  = tcx[eidx];
    }
    __syncthreads();

    // ---- partial dots: 4 cols x 8 batches over 32 k ----
    float acc[4][8];
#pragma unroll
    for (int ci = 0; ci < 4; ci++)
#pragma unroll
      for (int b2 = 0; b2 < 8; b2++) acc[ci][b2] = 0.f;

    const float* hb = hl + r * 36;
#pragma unroll
    for (int b2 = 0; b2 < 8; b2++) {
#pragma unroll
      for (int kc = 0; kc < 32; kc += 4) {
        float4 hv = *(const float4*)(hb + b2 * 576 + kc);
#pragma unroll
        for (int ci = 0; ci < 4; ci++) {
          acc[ci][b2] = fmaf(wreg[ci][kc + 0], hv.x, acc[ci][b2]);
          acc[ci][b2] = fmaf(wreg[ci][kc + 1], hv.y, acc[ci][b2]);
          acc[ci][b2] = fmaf(wreg[ci][kc + 2], hv.z, acc[ci][b2]);
          acc[ci][b2] = fmaf(wreg[ci][kc + 3], hv.w, acc[ci][b2]);
        }
      }
    }

    // ---- reduce over 16 k-ranges: butterfly within wave, LDS across waves ----
#pragma unroll
    for (int ci = 0; ci < 4; ci++)
#pragma unroll
      for (int b2 = 0; b2 < 8; b2++) {
        float v = acc[ci][b2];
        v += __shfl_xor(v, 16, 64);
        v += __shfl_xor(v, 32, 64);
        acc[ci][b2] = v;
      }
    if (ln < 16) {
#pragma unroll
      for (int ci = 0; ci < 4; ci++)
#pragma unroll
        for (int b2 = 0; b2 < 8; b2++)
          red[wv * 528 + ln * 33 + ci * 8 + b2] = acc[ci][b2];
    }
    __syncthreads();

    // ---- epilogue: 128 (b,j) pairs ----
    if (tid < 128) {
      float vals[4];
#pragma unroll
      for (int g2 = 0; g2 < 4; g2++) {
        int c = ejl * 4 + g2;
        int o = (c & 15) * 33 + (c >> 4) * 8 + eb;
        vals[g2] = red[o] + red[528 + o] + red[1056 + o] + red[1584 + o];
      }
      float iwv = vals[0] + bw;
      float imv = vals[1] + bm;
      float isv = vals[2] + bs;
      float tch = vals[3];
      float h_old = hl[eb * 576 + (ej >> 5) * 36 + (ej & 31)];
      float z   = tcx_v + tch;
      float tau = fmaxf(z, 0.f) + log1pf(expf(-fabsf(z))) + 0.1f;  // softplus+0.1
      float sig = 1.f / (1.f + expf(-imv));
      float inter = iwv * sig * expf(fminf(isv, 50.f));
      float dh  = (sens_v + inter - h_old) / fmaxf(tau, 1e-8f);
      float hnew = h_old + 0.1f * dh;
      out[eidx] = hnew;                              // overwrite sens in place
      hdst[bg * 4096 + eb * 512 + ej] = hnew;
    }

    // ---- per-group barrier (skip after last step) ----
    if (t != NT - 1) {
      __syncthreads();
      if (tid == 0) {
        __threadfence();
        unsigned old = __hip_atomic_fetch_add(cnt, 1u, __ATOMIC_ACQ_REL,
                                              __HIP_MEMORY_SCOPE_AGENT);
        if (old == (unsigned)(32 * (t + 1) - 1)) {
          __hip_atomic_store(gen, (unsigned)(t + 1), __ATOMIC_RELEASE,
                             __HIP_MEMORY_SCOPE_AGENT);
        }
        while (__hip_atomic_load(gen, __ATOMIC_ACQUIRE,
                                 __HIP_MEMORY_SCOPE_AGENT) < (unsigned)(t + 1)) {
          __builtin_amdgcn_s_sleep(2);
        }
      }
      __syncthreads();
    }
  }
}

// ---------------------------------------------------------------------------
extern "C" void kernel_launch(void* const* d_in, const int* in_sizes, int n_in,
                              void* d_out, int out_size, void* d_ws, size_t ws_size,
                              hipStream_t stream) {
  const float* x    = (const float*)d_in[0];
  const float* Wsw  = (const float*)d_in[1];
  const float* bsw  = (const float*)d_in[2];
  const float* Wsm  = (const float*)d_in[3];
  const float* bsm  = (const float*)d_in[4];
  const float* Wss  = (const float*)d_in[5];
  const float* bss  = (const float*)d_in[6];
  const float* Wiw  = (const float*)d_in[7];
  const float* biw  = (const float*)d_in[8];
  const float* Wim  = (const float*)d_in[9];
  const float* bim  = (const float*)d_in[10];
  const float* Wis  = (const float*)d_in[11];
  const float* bis  = (const float*)d_in[12];
  const float* Wtcx = (const float*)d_in[13];
  const float* Wtch = (const float*)d_in[14];
  const float* btc  = (const float*)d_in[15];
  float* out = (float*)d_out;

  // workspace (floats): WT_in[128*2048] | tcx[B*T*H] | h[2*B*H] | bar[256 u32]
  float* ws     = (float*)d_ws;
  float* WT_in  = ws;
  float* tcx    = ws + 262144;
  float* hbuf   = tcx + (size_t)NB * NT * NH;
  unsigned* bar = (unsigned*)(hbuf + 2 * NB * NH);

  hipLaunchKernelGGL(prep_kernel, dim3(256), dim3(256), 0, stream,
                     Wsw, Wsm, Wss, Wtcx, WT_in, hbuf, bar);

  hipLaunchKernelGGL(phase1_kernel, dim3(NB * NT / 32), dim3(256), 0, stream,
                     x, WT_in, bsw, bsm, bss, btc, out, tcx);

  hipLaunchKernelGGL(phase2_kernel, dim3(256), dim3(256), 0, stream,
                     Wiw, Wim, Wis, Wtch, biw, bim, bis,
                     tcx, out, hbuf, bar);
}

// Round 4
// 8148.530 us; speedup vs baseline: 2.6236x; 2.6236x over previous
//
#include <hip/hip_runtime.h>
#include <math.h>

#define NB 64
#define NT 1024
#define NI 128
#define NH 512

typedef unsigned long long u64;

// ---------------------------------------------------------------------------
// prep: transpose input-proj weights to k-major [k][j*4+m]; init tagged h
// buffer (both parities): tag=0, value=1.0f.
// ---------------------------------------------------------------------------
__global__ __launch_bounds__(256) void prep_kernel(
    const float* __restrict__ Wsw, const float* __restrict__ Wsm,
    const float* __restrict__ Wss, const float* __restrict__ Wtcx,
    float* __restrict__ WT_in, u64* __restrict__ htag)
{
  int idx = blockIdx.x * blockDim.x + threadIdx.x;
  int np  = gridDim.x * blockDim.x;
  for (int i = idx; i < NH * NI; i += np) {
    int j = i >> 7, k = i & 127;            // W is [H][I] row-major
    int o = k * 2048 + j * 4;
    WT_in[o + 0] = Wsw[i];
    WT_in[o + 1] = Wsm[i];
    WT_in[o + 2] = Wss[i];
    WT_in[o + 3] = Wtcx[i];
  }
  // {tag=0, 1.0f} in both parity halves
  for (int i = idx; i < 2 * NB * NH; i += np) htag[i] = 0x3F800000ULL;
}

// ---------------------------------------------------------------------------
// phase1: sensory + tcx for all (b,t).  Block = 32 rows x all 512 j.
// ---------------------------------------------------------------------------
__global__ __launch_bounds__(256, 2) void phase1_kernel(
    const float* __restrict__ x, const float* __restrict__ WT_in,
    const float* __restrict__ bsw, const float* __restrict__ bsm,
    const float* __restrict__ bss, const float* __restrict__ btc,
    float* __restrict__ sens, float* __restrict__ tcx)
{
  __shared__ __align__(16) float xs[32 * NI];   // 16 KB
  const int tid = threadIdx.x;
  const int n0  = blockIdx.x * 32;

  const float4* xsrc = (const float4*)(x + (size_t)n0 * NI);
#pragma unroll
  for (int i = 0; i < 4; i++)
    ((float4*)xs)[i * 256 + tid] = xsrc[i * 256 + tid];
  __syncthreads();

  for (int jj = 0; jj < 2; jj++) {
    const int j = tid + jj * 256;
    float4 acc[32];
#pragma unroll
    for (int n = 0; n < 32; n++) acc[n] = make_float4(0.f, 0.f, 0.f, 0.f);

    const float4* wp = (const float4*)WT_in + j;   // row k at wp[k*512]
#pragma unroll 2
    for (int k = 0; k < NI; k++) {
      float4 w = wp[(size_t)k * 512];
#pragma unroll
      for (int n = 0; n < 32; n++) {
        float xv = xs[n * NI + k];
        acc[n].x = fmaf(xv, w.x, acc[n].x);
        acc[n].y = fmaf(xv, w.y, acc[n].y);
        acc[n].z = fmaf(xv, w.z, acc[n].z);
        acc[n].w = fmaf(xv, w.w, acc[n].w);
      }
    }
    const float b0 = bsw[j], b1 = bsm[j], b2v = bss[j], b3 = btc[j];
#pragma unroll 4
    for (int n = 0; n < 32; n++) {
      float sw = acc[n].x + b0;
      float sm = acc[n].y + b1;
      float ss = acc[n].z + b2v;
      float tc = acc[n].w + b3;
      float sig = 1.f / (1.f + expf(-sm));
      float se  = expf(fminf(ss, 50.f));
      size_t o = (size_t)(n0 + n) * NH + j;
      sens[o] = sw * sig * se;
      tcx[o]  = tc;
    }
  }
}

// ---------------------------------------------------------------------------
// phase2: persistent recurrent scan, FENCE-FREE h exchange.
// 256 blocks = 8 batch-groups x 32 j-slices; weights VGPR-resident.
// h elements are published as 64-bit {tag=t+1, float} words via RELAXED
// agent-scope atomics (bypass non-coherent L2, served at the die-level
// coherence point -> no L2 writeback/invalidate, unlike the round-3
// acquire/release barrier that cost ~18 us/step in cache maintenance).
// Readers batch-load 16 words/lane, re-poll only stale tags.  Correctness:
// every tagged write data-depends on ALL of its block's tagged reads for
// that batch (full-K dot product), so tag==t proves the writer consumed all
// tag==t-1 inputs; parity double-buffering is then race-free with no
// ordering primitives and no XCD-placement assumptions.
// ---------------------------------------------------------------------------
__global__ __launch_bounds__(256, 1) void phase2_kernel(
    const float* __restrict__ Wiw, const float* __restrict__ Wim,
    const float* __restrict__ Wis, const float* __restrict__ Wtch,
    const float* __restrict__ biw, const float* __restrict__ bim,
    const float* __restrict__ bis,
    const float* __restrict__ tcx, float* __restrict__ out,
    u64* __restrict__ htag)
{
  __shared__ __align__(16) float hl[8 * 576];   // skewed h tile
  __shared__ float red[4 * 528];                // reduction scratch

  const int tid = threadIdx.x;
  const int wv  = tid >> 6;
  const int ln  = tid & 63;
  const int bg  = blockIdx.x & 7;
  const int js  = blockIdx.x >> 3;

  const int cg = ln & 15;
  const int r  = wv * 4 + (ln >> 4);   // k-range id 0..15
  const int k0 = r << 5;

  // persistent weights (128 VGPRs): col c = cg + 16*ci, gate g = cg&3
  const int g   = cg & 3;
  const int jl0 = cg >> 2;
  const float* Wp = (g == 0) ? Wiw : (g == 1) ? Wim : (g == 2) ? Wis : Wtch;
  float wreg[4][32];
#pragma unroll
  for (int ci = 0; ci < 4; ci++) {
    const float* wrow = Wp + (size_t)(js * 16 + jl0 + 4 * ci) * NH + k0;
#pragma unroll
    for (int kk = 0; kk < 32; kk++) wreg[ci][kk] = wrow[kk];
  }

  // epilogue-thread constants (tid<128 handles (b = tid>>4, jl = tid&15))
  const int ejl = tid & 15;
  const int eb  = tid >> 4;
  const int ej  = js * 16 + ejl;
  float bw = 0.f, bm = 0.f, bs = 0.f;
  if (tid < 128) { bw = biw[ej]; bm = bim[ej]; bs = bis[ej]; }

  u64* const hgrp0 = htag + bg * 4096;            // parity 0
  u64* const hgrp1 = htag + NB * NH + bg * 4096;  // parity 1

  for (int t = 0; t < NT; t++) {
    u64* hsrc = (t & 1) ? hgrp1 : hgrp0;
    u64* hdst = (t & 1) ? hgrp0 : hgrp1;
    const unsigned want = (unsigned)t;

    // ---- prefetch sens/tcx early (consumed in epilogue) ----
    float sens_v = 0.f, tcx_v = 0.f;
    size_t eidx = 0;
    if (tid < 128) {
      eidx   = ((size_t)(bg * 8 + eb) * NT + t) * NH + ej;
      sens_v = out[eidx];
      tcx_v  = tcx[eidx];
    }

    // ---- batched tagged load of h(t): 16 words/lane, re-poll stale ----
    u64 w[16];
#pragma unroll
    for (int i = 0; i < 16; i++)
      w[i] = __hip_atomic_load(hsrc + i * 256 + tid, __ATOMIC_RELAXED,
                               __HIP_MEMORY_SCOPE_AGENT);
    for (;;) {
      bool ok = true;
#pragma unroll
      for (int i = 0; i < 16; i++) ok = ok && ((unsigned)(w[i] >> 32) == want);
      if (ok) break;
      __builtin_amdgcn_s_sleep(2);
#pragma unroll
      for (int i = 0; i < 16; i++)
        if ((unsigned)(w[i] >> 32) != want)
          w[i] = __hip_atomic_load(hsrc + i * 256 + tid, __ATOMIC_RELAXED,
                                   __HIP_MEMORY_SCOPE_AGENT);
    }

    // ---- scatter to skewed LDS tile ----
#pragma unroll
    for (int i = 0; i < 16; i++) {
      int f  = i * 256 + tid;
      int b2 = f >> 9, k = f & 511;
      hl[b2 * 576 + (k >> 5) * 36 + (k & 31)] =
          __uint_as_float((unsigned)(w[i] & 0xFFFFFFFFull));
    }
    __syncthreads();   // (A) tile visible; also protects red[] across steps

    // ---- partial dots: 4 cols x 8 batches over 32 k ----
    float acc[4][8];
#pragma unroll
    for (int ci = 0; ci < 4; ci++)
#pragma unroll
      for (int b2 = 0; b2 < 8; b2++) acc[ci][b2] = 0.f;

    const float* hb = hl + r * 36;
#pragma unroll
    for (int b2 = 0; b2 < 8; b2++) {
#pragma unroll
      for (int kc = 0; kc < 32; kc += 4) {
        float4 hv = *(const float4*)(hb + b2 * 576 + kc);
#pragma unroll
        for (int ci = 0; ci < 4; ci++) {
          acc[ci][b2] = fmaf(wreg[ci][kc + 0], hv.x, acc[ci][b2]);
          acc[ci][b2] = fmaf(wreg[ci][kc + 1], hv.y, acc[ci][b2]);
          acc[ci][b2] = fmaf(wreg[ci][kc + 2], hv.z, acc[ci][b2]);
          acc[ci][b2] = fmaf(wreg[ci][kc + 3], hv.w, acc[ci][b2]);
        }
      }
    }

    // ---- reduce over 16 k-ranges ----
#pragma unroll
    for (int ci = 0; ci < 4; ci++)
#pragma unroll
      for (int b2 = 0; b2 < 8; b2++) {
        float v = acc[ci][b2];
        v += __shfl_xor(v, 16, 64);
        v += __shfl_xor(v, 32, 64);
        acc[ci][b2] = v;
      }
    if (ln < 16) {
#pragma unroll
      for (int ci = 0; ci < 4; ci++)
#pragma unroll
        for (int b2 = 0; b2 < 8; b2++)
          red[wv * 528 + ln * 33 + ci * 8 + b2] = acc[ci][b2];
    }
    // h_old read BEFORE barrier (B): hl stays untouched until after (B)
    float h_old = 0.f;
    if (tid < 128) h_old = hl[eb * 576 + (ej >> 5) * 36 + (ej & 31)];
    __syncthreads();   // (B) red visible

    // ---- epilogue: 128 (b,j) pairs ----
    if (tid < 128) {
      float vals[4];
#pragma unroll
      for (int g2 = 0; g2 < 4; g2++) {
        int c = ejl * 4 + g2;
        int o = (c & 15) * 33 + (c >> 4) * 8 + eb;
        vals[g2] = red[o] + red[528 + o] + red[1056 + o] + red[1584 + o];
      }
      float iwv = vals[0] + bw;
      float imv = vals[1] + bm;
      float isv = vals[2] + bs;
      float tch = vals[3];
      float z   = tcx_v + tch;
      float tau = fmaxf(z, 0.f) + log1pf(expf(-fabsf(z))) + 0.1f;  // softplus+0.1
      float sig = 1.f / (1.f + expf(-imv));
      float inter = iwv * sig * expf(fminf(isv, 50.f));
      float dh  = (sens_v + inter - h_old) / fmaxf(tau, 1e-8f);
      float hnew = h_old + 0.1f * dh;
      out[eidx] = hnew;                              // overwrite sens in place
      u64 nw = ((u64)(unsigned)(t + 1) << 32) | (u64)__float_as_uint(hnew);
      __hip_atomic_store(hdst + eb * 512 + ej, nw, __ATOMIC_RELAXED,
                         __HIP_MEMORY_SCOPE_AGENT);
    }
    // no end-of-step barrier needed: next scatter's hl writes only happen
    // after that wave passes (B), and all hl reads precede (B).
  }
}

// ---------------------------------------------------------------------------
extern "C" void kernel_launch(void* const* d_in, const int* in_sizes, int n_in,
                              void* d_out, int out_size, void* d_ws, size_t ws_size,
                              hipStream_t stream) {
  const float* x    = (const float*)d_in[0];
  const float* Wsw  = (const float*)d_in[1];
  const float* bsw  = (const float*)d_in[2];
  const float* Wsm  = (const float*)d_in[3];
  const float* bsm  = (const float*)d_in[4];
  const float* Wss  = (const float*)d_in[5];
  const float* bss  = (const float*)d_in[6];
  const float* Wiw  = (const float*)d_in[7];
  const float* biw  = (const float*)d_in[8];
  const float* Wim  = (const float*)d_in[9];
  const float* bim  = (const float*)d_in[10];
  const float* Wis  = (const float*)d_in[11];
  const float* bis  = (const float*)d_in[12];
  const float* Wtcx = (const float*)d_in[13];
  const float* Wtch = (const float*)d_in[14];
  const float* btc  = (const float*)d_in[15];
  float* out = (float*)d_out;

  // workspace (floats): WT_in[128*2048] | tcx[B*T*H] | htag[2*B*H u64]
  float* ws     = (float*)d_ws;
  float* WT_in  = ws;
  float* tcx    = ws + 262144;
  u64*   htag   = (u64*)(tcx + (size_t)NB * NT * NH);

  hipLaunchKernelGGL(prep_kernel, dim3(256), dim3(256), 0, stream,
                     Wsw, Wsm, Wss, Wtcx, WT_in, htag);

  hipLaunchKernelGGL(phase1_kernel, dim3(NB * NT / 32), dim3(256), 0, stream,
                     x, WT_in, bsw, bsm, bss, btc, out, tcx);

  hipLaunchKernelGGL(phase2_kernel, dim3(256), dim3(256), 0, stream,
                     Wiw, Wim, Wis, Wtch, biw, bim, bis,
                     tcx, out, htag);
}